// Round 10
// baseline (336.328 us; speedup 1.0000x reference)
//
#include <hip/hip_runtime.h>
#include <stdint.h>

// Problem constants
#define NN 4096
#define KSEL 1677721u            // int(4096*4096*0.1)
#define INV_SQRT_DK 0.17677669529663687f  // 1/sqrt(32)

// Workspace layout (bytes)
#define OFF_PQ 0u                     // Q partials fp32 [4][4096*128] = 8 MB (dead after combine)
#define OFF_PK (8u<<20)               // K partials 8 MB
#define OFF_QH (16u<<20)              // bf16 Q 1 MB
#define OFF_KH (17u<<20)              // bf16 K 1 MB
#define OFF_STATS (18u<<20)           // 4096 * float2 = 32 KB
// hist reuses dead partial region after combine:
#define OFF_H   0u                    // 256 partial hists x 1024 u32 = 1 MB
#define OFF_H2  (1u<<20)              // 8 partial hists = 32 KB
#define OFF_ST  ((1u<<20) + 65536u)   // state
#define OFF_SB  (32u<<20)             // bf16 scores 32 MB
#define WS_NEED_B16 (64u<<20)
#define QTR_ELEMS 524288u             // 4096*128 floats per quarter-partial

typedef __attribute__((ext_vector_type(8))) short bf16x8;
typedef __attribute__((ext_vector_type(8))) unsigned short u16x8;
typedef __attribute__((ext_vector_type(4))) float f32x4;

static __device__ __forceinline__ short f2bf(float f) {
    unsigned u = __float_as_uint(f);
    unsigned r = (u + 0x7FFFu + ((u >> 16) & 1u)) >> 16;   // RNE
    return (short)r;
}
static __device__ __forceinline__ float bf2f(short h) {
    return __uint_as_float(((unsigned)(unsigned short)h) << 16);
}

// ---------------------------------------------------------------------------
// 1) Projection partial sums (fp32), R8 structure (SGPR-broadcast W: 64 FMA
//    per 64-float s_load batch). Grid 1024 = b(4) x ntile(64) x fquarter(4);
//    8 waves, wave f-chunk = 2. launch_bounds(512,8) -> VGPR<=64 (R8 used 56)
//    guarantees 4 blocks/CU = 32 waves/CU to hide the s_load->FMA chain.
// ---------------------------------------------------------------------------
__global__ __launch_bounds__(512, 8) void proj_kernel(
    const float* __restrict__ x, const float* __restrict__ WQ,
    const float* __restrict__ WK,
    float* __restrict__ Qp, float* __restrict__ Kp)
{
    __shared__ float red[8 * 64 * 17];
    const int bx  = blockIdx.x;
    const int b   = bx >> 8;
    const int n0  = ((bx >> 2) & 63) << 6;
    const int fq  = bx & 3;
    const int tid = threadIdx.x;
    const int l   = tid & 63;
    const int w   = __builtin_amdgcn_readfirstlane(tid >> 6);
    const int n   = n0 + l;

    float* __restrict__ Qdst = Qp + (size_t)fq * QTR_ELEMS;
    float* __restrict__ Kdst = Kp + (size_t)fq * QTR_ELEMS;

    float accQ[32], accK[32];
#pragma unroll
    for (int j = 0; j < 32; ++j) { accQ[j] = 0.f; accK[j] = 0.f; }

    const int fg0 = fq * 16 + w * 2;
    const float* xp = x + (size_t)b * 3145728 + (size_t)fg0 * 49152 + (size_t)n * 12;

    for (int f = 0; f < 2; ++f) {
        float4 a0 = *(const float4*)(xp);
        float4 a1 = *(const float4*)(xp + 4);
        float4 a2 = *(const float4*)(xp + 8);
        const float xv[12] = {a0.x, a0.y, a0.z, a0.w,
                              a1.x, a1.y, a1.z, a1.w,
                              a2.x, a2.y, a2.z, a2.w};
        const int fg = fg0 + f;
#pragma unroll
        for (int t = 0; t < 12; ++t) {
            const float* __restrict__ wq = WQ + (size_t)(((t << 6) + fg) << 5);
            const float* __restrict__ wk = WK + (size_t)(((t << 6) + fg) << 5);
            const float xt = xv[t];
#pragma unroll
            for (int j = 0; j < 32; ++j) {
                accQ[j] = fmaf(xt, wq[j], accQ[j]);
                accK[j] = fmaf(xt, wk[j], accK[j]);
            }
        }
        xp += 49152;
    }

    for (int p = 0; p < 4; ++p) {
        const float* src = (p < 2) ? accQ : accK;
        const int off = (p & 1) << 4;
        float* rp = &red[(w * 64 + l) * 17];
#pragma unroll
        for (int j = 0; j < 16; ++j) rp[j] = src[off + j];
        __syncthreads();
#pragma unroll
        for (int h = 0; h < 2; ++h) {
            int o = tid + h * 512;
            int r_ = o >> 4, c = o & 15;
            float s = 0.f;
#pragma unroll
            for (int w2 = 0; w2 < 8; ++w2) s += red[(w2 * 64 + r_) * 17 + c];
            size_t idx = (size_t)(n0 + r_) * 128 + (b << 5) + ((p & 1) << 4) + c;
            if (p < 2) Qdst[idx] = s; else Kdst[idx] = s;
        }
        __syncthreads();
    }
}

// ---------------------------------------------------------------------------
// 1b) Combine 4 f-quarters, scale Q, round to bf16. Grid 512x256.
// ---------------------------------------------------------------------------
__global__ __launch_bounds__(256) void combine_kernel(
    const float4* __restrict__ Qp, const float4* __restrict__ Kp,
    short* __restrict__ Qh, short* __restrict__ Kh)
{
    const size_t i = (size_t)blockIdx.x * 256 + threadIdx.x;
    const size_t stride = QTR_ELEMS / 4;
    float4 q0 = Qp[i],             q1 = Qp[i + stride];
    float4 q2 = Qp[i + 2 * stride], q3 = Qp[i + 3 * stride];
    float4 k0 = Kp[i],             k1 = Kp[i + stride];
    float4 k2 = Kp[i + 2 * stride], k3 = Kp[i + 3 * stride];
    short4 qh, kh;
    qh.x = f2bf((q0.x + q1.x + q2.x + q3.x) * INV_SQRT_DK);
    qh.y = f2bf((q0.y + q1.y + q2.y + q3.y) * INV_SQRT_DK);
    qh.z = f2bf((q0.z + q1.z + q2.z + q3.z) * INV_SQRT_DK);
    qh.w = f2bf((q0.w + q1.w + q2.w + q3.w) * INV_SQRT_DK);
    kh.x = f2bf(k0.x + k1.x + k2.x + k3.x);
    kh.y = f2bf(k0.y + k1.y + k2.y + k3.y);
    kh.z = f2bf(k0.z + k1.z + k2.z + k3.z);
    kh.w = f2bf(k0.w + k1.w + k2.w + k3.w);
    *(short4*)(Qh + 4 * i) = qh;
    *(short4*)(Kh + 4 * i) = kh;
}

// ---------------------------------------------------------------------------
// 2) S = Q @ K^T via MFMA 16x16x32 bf16. 128x128 tile per 256-thread block,
//    wave tile 64x64 (4x4 frags), 2-deep register ping-pong prefetch.
// ---------------------------------------------------------------------------
template<bool B16>
__global__ __launch_bounds__(256, 3) void gemm_kernel(
    const short* __restrict__ Qh, const short* __restrict__ Kh, void* Sv)
{
    const int bi = blockIdx.x >> 5, bj = blockIdx.x & 31;
    const int tid = threadIdx.x;
    const int w = tid >> 6, l = tid & 63;
    const int m0 = bi * 128 + (w >> 1) * 64;
    const int n0 = bj * 128 + (w & 1) * 64;
    const int lr = l & 15;
    const int kg = (l >> 4) * 8;

    f32x4 acc[4][4];
#pragma unroll
    for (int i = 0; i < 4; ++i)
#pragma unroll
        for (int j = 0; j < 4; ++j) acc[i][j] = (f32x4){0.f, 0.f, 0.f, 0.f};

    bf16x8 aA[4], bA[4], aB[4], bB[4];

    auto LD = [&](bf16x8* A, bf16x8* B, int k0) {
#pragma unroll
        for (int i = 0; i < 4; ++i) {
            A[i] = *(const bf16x8*)(Qh + (size_t)(m0 + i * 16 + lr) * 128 + k0 + kg);
            B[i] = *(const bf16x8*)(Kh + (size_t)(n0 + i * 16 + lr) * 128 + k0 + kg);
        }
    };
    auto DOMFMA = [&](bf16x8* A, bf16x8* B) {
#pragma unroll
        for (int i = 0; i < 4; ++i)
#pragma unroll
            for (int j = 0; j < 4; ++j)
                acc[i][j] = __builtin_amdgcn_mfma_f32_16x16x32_bf16(A[i], B[j], acc[i][j], 0, 0, 0);
    };

    LD(aA, bA, 0);
    LD(aB, bB, 32);
    DOMFMA(aA, bA);  LD(aA, bA, 64);
    DOMFMA(aB, bB);  LD(aB, bB, 96);
    DOMFMA(aA, bA);
    DOMFMA(aB, bB);

    // C/D mapping (m89-verified): col = lane&15, row = (lane>>4)*4 + reg
#pragma unroll
    for (int i = 0; i < 4; ++i) {
        int rowb = m0 + i * 16 + (l >> 4) * 4;
#pragma unroll
        for (int j = 0; j < 4; ++j) {
            int col = n0 + j * 16 + (l & 15);
#pragma unroll
            for (int r = 0; r < 4; ++r) {
                if constexpr (B16)
                    ((unsigned short*)Sv)[(size_t)(rowb + r) * NN + col] =
                        (unsigned short)f2bf(acc[i][j][r]);
                else
                    ((float*)Sv)[(size_t)(rowb + r) * NN + col] = acc[i][j][r];
            }
        }
    }
}

// ---------------------------------------------------------------------------
// 3) Fused row stats + histogram. One wave per row, row in registers.
//    Each block OWNS partial-hist slot blockIdx.x (full overwrite, no memset).
// ---------------------------------------------------------------------------
template<bool B16>
__global__ __launch_bounds__(512) void histstat_kernel(
    const void* __restrict__ Sv, float2* __restrict__ stats,
    unsigned* __restrict__ gh)
{
    __shared__ unsigned h[1024];
    const int tid = threadIdx.x;
    const int l = tid & 63;
    const int w = tid >> 6;

    for (int i = tid; i < 1024; i += 512) h[i] = 0;
    __syncthreads();

#pragma unroll
    for (int r = 0; r < 2; ++r) {
        const int row = (blockIdx.x << 4) + (r << 3) + w;

        float v[64];
        if constexpr (B16) {
            const u16x8* rp = (const u16x8*)((const unsigned short*)Sv + (size_t)row * NN);
#pragma unroll
            for (int j = 0; j < 8; ++j) {
                u16x8 e = rp[l + (j << 6)];
#pragma unroll
                for (int i = 0; i < 8; ++i) v[j * 8 + i] = bf2f((short)e[i]);
            }
        } else {
            const float4* rp = (const float4*)((const float*)Sv + (size_t)row * NN);
#pragma unroll
            for (int j = 0; j < 16; ++j) {
                float4 t = rp[l + (j << 6)];
                v[j * 4 + 0] = t.x; v[j * 4 + 1] = t.y;
                v[j * 4 + 2] = t.z; v[j * 4 + 3] = t.w;
            }
        }

        float m = -3.4e38f;
#pragma unroll
        for (int j = 0; j < 64; ++j) m = fmaxf(m, v[j]);
#pragma unroll
        for (int off = 32; off; off >>= 1) m = fmaxf(m, __shfl_xor(m, off));

        float s = 0.f;
#pragma unroll
        for (int j = 0; j < 64; ++j) { v[j] = __expf(v[j] - m); s += v[j]; }
#pragma unroll
        for (int off = 32; off; off >>= 1) s += __shfl_xor(s, off);
        const float inv = 1.0f / s;
        if (l == 0) stats[row] = make_float2(m, inv);

#pragma unroll
        for (int j = 0; j < 64; ++j) {
            int b0 = min(max((int)(__float_as_uint(v[j] * inv) >> 16) - 0x3780, 0), 1023);
            atomicAdd(&h[b0], 1u);
        }
    }

    __syncthreads();
    unsigned* dst = gh + ((unsigned)blockIdx.x << 10);
    for (int i = tid; i < 1024; i += 512) dst[i] = h[i];   // full overwrite
}

// ---------------------------------------------------------------------------
// 4a) Pre-reduce 256 partials -> 8.   4b) Final reduce + suffix-scan.
// ---------------------------------------------------------------------------
__global__ __launch_bounds__(1024) void reduce_kernel(
    const unsigned* __restrict__ gh, unsigned* __restrict__ gh2)
{
    const int t = threadIdx.x, b = blockIdx.x;
    unsigned s = 0;
    for (int p = 0; p < 32; ++p) s += gh[((unsigned)(b * 32 + p) << 10) + t];
    gh2[((unsigned)b << 10) + t] = s;
}

__global__ __launch_bounds__(1024) void scan_kernel(
    const unsigned* __restrict__ gh2, unsigned* st)
{
    __shared__ unsigned P[1024];
    const int t = threadIdx.x;
    unsigned s = 0;
#pragma unroll
    for (int p = 0; p < 8; ++p) s += gh2[(p << 10) + t];
    P[t] = s;
    __syncthreads();
    for (int off = 1; off < 1024; off <<= 1) {
        unsigned v = P[t] + ((t + off < 1024) ? P[t + off] : 0u);
        __syncthreads();
        P[t] = v;
        __syncthreads();
    }
    if (P[t] >= KSEL && (t == 1023 || P[t + 1] < KSEL))
        st[2] = (0x3780u + (unsigned)t) << 16;   // lower edge of selected bin
}

// ---------------------------------------------------------------------------
// 5) Final: recompute p, threshold -> keep; else dropout (x1/0.9 or 0).
// ---------------------------------------------------------------------------
template<bool B16>
__global__ __launch_bounds__(256) void final_kernel(
    const void* __restrict__ Sv, float* __restrict__ out,
    const float4* __restrict__ u4,
    const float2* __restrict__ stats, const unsigned* __restrict__ st)
{
    const int row = blockIdx.x;
    const float thr = __uint_as_float(st[2]);
    const float2 stt = stats[row];
    float4* o4 = (float4*)(out + (size_t)row * NN);
    const float4* u = u4 + (size_t)row * 1024;
    for (int i = threadIdx.x; i < 1024; i += 256) {
        float4 v;
        if constexpr (B16) {
            ushort4 s4 = ((const ushort4*)((const unsigned short*)Sv + (size_t)row * NN))[i];
            v.x = bf2f((short)s4.x); v.y = bf2f((short)s4.y);
            v.z = bf2f((short)s4.z); v.w = bf2f((short)s4.w);
        } else {
            v = ((const float4*)((const float*)Sv + (size_t)row * NN))[i];
        }
        float4 uu = u[i];
        float4 o;
        float p;
        p = __expf(v.x - stt.x) * stt.y;
        o.x = (p >= thr) ? p : ((uu.x >= 0.1f) ? p * (1.0f / 0.9f) : 0.0f);
        p = __expf(v.y - stt.x) * stt.y;
        o.y = (p >= thr) ? p : ((uu.y >= 0.1f) ? p * (1.0f / 0.9f) : 0.0f);
        p = __expf(v.z - stt.x) * stt.y;
        o.z = (p >= thr) ? p : ((uu.z >= 0.1f) ? p * (1.0f / 0.9f) : 0.0f);
        p = __expf(v.w - stt.x) * stt.y;
        o.w = (p >= thr) ? p : ((uu.w >= 0.1f) ? p * (1.0f / 0.9f) : 0.0f);
        o4[i] = o;
    }
}

extern "C" void kernel_launch(void* const* d_in, const int* in_sizes, int n_in,
                              void* d_out, int out_size, void* d_ws, size_t ws_size,
                              hipStream_t stream)
{
    const float* x  = (const float*)d_in[0];
    const float* WQ = (const float*)d_in[1];
    const float* WK = (const float*)d_in[2];
    const float* du = (const float*)d_in[3];
    float* out = (float*)d_out;
    char* ws = (char*)d_ws;

    float* Qp = (float*)(ws + OFF_PQ);
    float* Kp = (float*)(ws + OFF_PK);
    short* Qh = (short*)(ws + OFF_QH);
    short* Kh = (short*)(ws + OFF_KH);
    float2* stats = (float2*)(ws + OFF_STATS);
    unsigned* hist = (unsigned*)(ws + OFF_H);    // reuses dead partial region
    unsigned* gh2  = (unsigned*)(ws + OFF_H2);
    unsigned* st   = (unsigned*)(ws + OFF_ST);

    proj_kernel<<<1024, 512, 0, stream>>>(x, WQ, WK, Qp, Kp);
    combine_kernel<<<512, 256, 0, stream>>>(
        (const float4*)Qp, (const float4*)Kp, Qh, Kh);

    const bool b16 = (ws_size >= (size_t)WS_NEED_B16);   // fixed per process -> graph-safe
    if (b16) {
        void* Sb = (void*)(ws + OFF_SB);
        gemm_kernel<true><<<1024, 256, 0, stream>>>(Qh, Kh, Sb);
        histstat_kernel<true><<<256, 512, 0, stream>>>(Sb, stats, hist);
        reduce_kernel<<<8, 1024, 0, stream>>>(hist, gh2);
        scan_kernel<<<1, 1024, 0, stream>>>(gh2, st);
        final_kernel<true><<<NN, 256, 0, stream>>>(Sb, out, (const float4*)du, stats, st);
    } else {
        gemm_kernel<false><<<1024, 256, 0, stream>>>(Qh, Kh, (void*)out);
        histstat_kernel<false><<<256, 512, 0, stream>>>((void*)out, stats, hist);
        reduce_kernel<<<8, 1024, 0, stream>>>(hist, gh2);
        scan_kernel<<<1, 1024, 0, stream>>>(gh2, st);
        final_kernel<false><<<NN, 256, 0, stream>>>((void*)out, out, (const float4*)du, stats, st);
    }
}

// Round 11
// 139.743 us; speedup vs baseline: 2.4068x; 2.4068x over previous
//
#include <hip/hip_runtime.h>
#include <stdint.h>

// Problem constants
#define NN 4096
#define KSEL 1677721u            // int(4096*4096*0.1)
#define INV_SQRT_DK 0.17677669529663687f  // 1/sqrt(32)

// Workspace layout (bytes)
#define OFF_QH 0u                     // bf16 Q [4096][128] = 1 MB
#define OFF_KH (1u<<20)               // bf16 K 1 MB
#define OFF_STATS (2u<<20)            // 4096 * float2 = 32 KB
#define OFF_H   (3u<<20)              // 256 partial hists x 1024 u32 = 1 MB
#define OFF_H2  (4u<<20)              // 8 partial hists = 32 KB
#define OFF_ST  ((4u<<20) + 65536u)   // state
#define OFF_SB  (16u<<20)             // bf16 scores 32 MB (only if ws >= 48MB)
#define WS_NEED_B16 (48u<<20)

typedef __attribute__((ext_vector_type(8))) short bf16x8;
typedef __attribute__((ext_vector_type(8))) unsigned short u16x8;
typedef __attribute__((ext_vector_type(4))) float f32x4;

static __device__ __forceinline__ short f2bf(float f) {
    unsigned u = __float_as_uint(f);
    unsigned r = (u + 0x7FFFu + ((u >> 16) & 1u)) >> 16;   // RNE
    return (short)r;
}
static __device__ __forceinline__ float bf2f(short h) {
    return __uint_as_float(((unsigned)(unsigned short)h) << 16);
}

// ---------------------------------------------------------------------------
// 1) Projection, LDS-staged, small-register design. Grid 1024 =
//    b(4) x 16-row tiles(256), 256 thr. Thread = (row 0..15, 4 cols of
//    [Q0..Q31 | K0..K31]). Per f: stage x-slice (192 fl) + W-slice (768 fl)
//    double-buffered (7.7 KB LDS); compute via broadcast ds_read_b128.
//    4 acc/thread -> ~35 VGPR, no spill (R10 lesson: 64 acc + tight cap
//    spilled to scratch at 1 GB traffic). W re-reads hit L2 (384 KB total).
// ---------------------------------------------------------------------------
__global__ __launch_bounds__(256, 4) void proj_kernel(
    const float* __restrict__ x, const float* __restrict__ WQ,
    const float* __restrict__ WK,
    short* __restrict__ Qh, short* __restrict__ Kh)
{
    __shared__ float xs[2][192];
    __shared__ float ws[2][768];
    const int bx  = blockIdx.x;
    const int b   = bx >> 8;
    const int n0  = (bx & 255) << 4;
    const int tid = threadIdx.x;
    const int row = tid >> 4;
    const int c0  = (tid & 15) << 2;   // 0..60 step 4

    float acc[4] = {0.f, 0.f, 0.f, 0.f};

    auto STAGE = [&](int f, int buf) {
        if (tid < 48) {
            float4 v = *(const float4*)(x + (size_t)b * 3145728
                                          + (size_t)f * 49152
                                          + (size_t)n0 * 12 + tid * 4);
            *(float4*)&xs[buf][tid * 4] = v;
        } else if (tid < 144) {
            const int idx = tid - 48, tt = idx >> 3, q = idx & 7;
            float4 v = *(const float4*)(WQ + (size_t)(((tt << 6) + f) << 5) + (q << 2));
            *(float4*)&ws[buf][tt * 64 + (q << 2)] = v;
        } else if (tid < 240) {
            const int idx = tid - 144, tt = idx >> 3, q = idx & 7;
            float4 v = *(const float4*)(WK + (size_t)(((tt << 6) + f) << 5) + (q << 2));
            *(float4*)&ws[buf][tt * 64 + 32 + (q << 2)] = v;
        }
    };

    STAGE(0, 0);
    int buf = 0;
    for (int f = 0; f < 64; ++f) {
        __syncthreads();                     // staged buf visible; prior reads done
        if (f < 63) STAGE(f + 1, buf ^ 1);   // prefetch next slice into other buf

        float4 xa = *(const float4*)&xs[buf][row * 12];
        float4 xb = *(const float4*)&xs[buf][row * 12 + 4];
        float4 xc = *(const float4*)&xs[buf][row * 12 + 8];
        const float xv[12] = {xa.x, xa.y, xa.z, xa.w,
                              xb.x, xb.y, xb.z, xb.w,
                              xc.x, xc.y, xc.z, xc.w};
#pragma unroll
        for (int tt = 0; tt < 12; ++tt) {
            float4 wv = *(const float4*)&ws[buf][tt * 64 + c0];
            const float xt = xv[tt];
            acc[0] = fmaf(xt, wv.x, acc[0]);
            acc[1] = fmaf(xt, wv.y, acc[1]);
            acc[2] = fmaf(xt, wv.z, acc[2]);
            acc[3] = fmaf(xt, wv.w, acc[3]);
        }
        buf ^= 1;
    }

    const int n = n0 + row;
    short4 o;
    if (c0 < 32) {
        o.x = f2bf(acc[0] * INV_SQRT_DK); o.y = f2bf(acc[1] * INV_SQRT_DK);
        o.z = f2bf(acc[2] * INV_SQRT_DK); o.w = f2bf(acc[3] * INV_SQRT_DK);
        *(short4*)(Qh + (size_t)n * 128 + (b << 5) + c0) = o;
    } else {
        o.x = f2bf(acc[0]); o.y = f2bf(acc[1]);
        o.z = f2bf(acc[2]); o.w = f2bf(acc[3]);
        *(short4*)(Kh + (size_t)n * 128 + (b << 5) + (c0 - 32)) = o;
    }
}

// ---------------------------------------------------------------------------
// 2) S = Q @ K^T via MFMA 16x16x32 bf16. 128x128 tile per 256-thread block,
//    wave tile 64x64 (4x4 frags), 2-deep register ping-pong prefetch.
// ---------------------------------------------------------------------------
template<bool B16>
__global__ __launch_bounds__(256, 3) void gemm_kernel(
    const short* __restrict__ Qh, const short* __restrict__ Kh, void* Sv)
{
    const int bi = blockIdx.x >> 5, bj = blockIdx.x & 31;
    const int tid = threadIdx.x;
    const int w = tid >> 6, l = tid & 63;
    const int m0 = bi * 128 + (w >> 1) * 64;
    const int n0 = bj * 128 + (w & 1) * 64;
    const int lr = l & 15;
    const int kg = (l >> 4) * 8;

    f32x4 acc[4][4];
#pragma unroll
    for (int i = 0; i < 4; ++i)
#pragma unroll
        for (int j = 0; j < 4; ++j) acc[i][j] = (f32x4){0.f, 0.f, 0.f, 0.f};

    bf16x8 aA[4], bA[4], aB[4], bB[4];

    auto LD = [&](bf16x8* A, bf16x8* B, int k0) {
#pragma unroll
        for (int i = 0; i < 4; ++i) {
            A[i] = *(const bf16x8*)(Qh + (size_t)(m0 + i * 16 + lr) * 128 + k0 + kg);
            B[i] = *(const bf16x8*)(Kh + (size_t)(n0 + i * 16 + lr) * 128 + k0 + kg);
        }
    };
    auto DOMFMA = [&](bf16x8* A, bf16x8* B) {
#pragma unroll
        for (int i = 0; i < 4; ++i)
#pragma unroll
            for (int j = 0; j < 4; ++j)
                acc[i][j] = __builtin_amdgcn_mfma_f32_16x16x32_bf16(A[i], B[j], acc[i][j], 0, 0, 0);
    };

    LD(aA, bA, 0);
    LD(aB, bB, 32);
    DOMFMA(aA, bA);  LD(aA, bA, 64);
    DOMFMA(aB, bB);  LD(aB, bB, 96);
    DOMFMA(aA, bA);
    DOMFMA(aB, bB);

    // C/D mapping (m89-verified): col = lane&15, row = (lane>>4)*4 + reg
#pragma unroll
    for (int i = 0; i < 4; ++i) {
        int rowb = m0 + i * 16 + (l >> 4) * 4;
#pragma unroll
        for (int j = 0; j < 4; ++j) {
            int col = n0 + j * 16 + (l & 15);
#pragma unroll
            for (int r = 0; r < 4; ++r) {
                if constexpr (B16)
                    ((unsigned short*)Sv)[(size_t)(rowb + r) * NN + col] =
                        (unsigned short)f2bf(acc[i][j][r]);
                else
                    ((float*)Sv)[(size_t)(rowb + r) * NN + col] = acc[i][j][r];
            }
        }
    }
}

// ---------------------------------------------------------------------------
// 3) Fused row stats + histogram. One wave per row, row in registers.
//    Each block OWNS partial-hist slot blockIdx.x (full overwrite, no memset).
// ---------------------------------------------------------------------------
template<bool B16>
__global__ __launch_bounds__(512) void histstat_kernel(
    const void* __restrict__ Sv, float2* __restrict__ stats,
    unsigned* __restrict__ gh)
{
    __shared__ unsigned h[1024];
    const int tid = threadIdx.x;
    const int l = tid & 63;
    const int w = tid >> 6;

    for (int i = tid; i < 1024; i += 512) h[i] = 0;
    __syncthreads();

#pragma unroll
    for (int r = 0; r < 2; ++r) {
        const int row = (blockIdx.x << 4) + (r << 3) + w;

        float v[64];
        if constexpr (B16) {
            const u16x8* rp = (const u16x8*)((const unsigned short*)Sv + (size_t)row * NN);
#pragma unroll
            for (int j = 0; j < 8; ++j) {
                u16x8 e = rp[l + (j << 6)];
#pragma unroll
                for (int i = 0; i < 8; ++i) v[j * 8 + i] = bf2f((short)e[i]);
            }
        } else {
            const float4* rp = (const float4*)((const float*)Sv + (size_t)row * NN);
#pragma unroll
            for (int j = 0; j < 16; ++j) {
                float4 t = rp[l + (j << 6)];
                v[j * 4 + 0] = t.x; v[j * 4 + 1] = t.y;
                v[j * 4 + 2] = t.z; v[j * 4 + 3] = t.w;
            }
        }

        float m = -3.4e38f;
#pragma unroll
        for (int j = 0; j < 64; ++j) m = fmaxf(m, v[j]);
#pragma unroll
        for (int off = 32; off; off >>= 1) m = fmaxf(m, __shfl_xor(m, off));

        float s = 0.f;
#pragma unroll
        for (int j = 0; j < 64; ++j) { v[j] = __expf(v[j] - m); s += v[j]; }
#pragma unroll
        for (int off = 32; off; off >>= 1) s += __shfl_xor(s, off);
        const float inv = 1.0f / s;
        if (l == 0) stats[row] = make_float2(m, inv);

#pragma unroll
        for (int j = 0; j < 64; ++j) {
            int b0 = min(max((int)(__float_as_uint(v[j] * inv) >> 16) - 0x3780, 0), 1023);
            atomicAdd(&h[b0], 1u);
        }
    }

    __syncthreads();
    unsigned* dst = gh + ((unsigned)blockIdx.x << 10);
    for (int i = tid; i < 1024; i += 512) dst[i] = h[i];   // full overwrite
}

// ---------------------------------------------------------------------------
// 4a) Pre-reduce 256 partials -> 8.   4b) Final reduce + suffix-scan.
// ---------------------------------------------------------------------------
__global__ __launch_bounds__(1024) void reduce_kernel(
    const unsigned* __restrict__ gh, unsigned* __restrict__ gh2)
{
    const int t = threadIdx.x, b = blockIdx.x;
    unsigned s = 0;
    for (int p = 0; p < 32; ++p) s += gh[((unsigned)(b * 32 + p) << 10) + t];
    gh2[((unsigned)b << 10) + t] = s;
}

__global__ __launch_bounds__(1024) void scan_kernel(
    const unsigned* __restrict__ gh2, unsigned* st)
{
    __shared__ unsigned P[1024];
    const int t = threadIdx.x;
    unsigned s = 0;
#pragma unroll
    for (int p = 0; p < 8; ++p) s += gh2[(p << 10) + t];
    P[t] = s;
    __syncthreads();
    for (int off = 1; off < 1024; off <<= 1) {
        unsigned v = P[t] + ((t + off < 1024) ? P[t + off] : 0u);
        __syncthreads();
        P[t] = v;
        __syncthreads();
    }
    if (P[t] >= KSEL && (t == 1023 || P[t + 1] < KSEL))
        st[2] = (0x3780u + (unsigned)t) << 16;   // lower edge of selected bin
}

// ---------------------------------------------------------------------------
// 5) Final: recompute p, threshold -> keep; else dropout (x1/0.9 or 0).
// ---------------------------------------------------------------------------
template<bool B16>
__global__ __launch_bounds__(256) void final_kernel(
    const void* __restrict__ Sv, float* __restrict__ out,
    const float4* __restrict__ u4,
    const float2* __restrict__ stats, const unsigned* __restrict__ st)
{
    const int row = blockIdx.x;
    const float thr = __uint_as_float(st[2]);
    const float2 stt = stats[row];
    float4* o4 = (float4*)(out + (size_t)row * NN);
    const float4* u = u4 + (size_t)row * 1024;
    for (int i = threadIdx.x; i < 1024; i += 256) {
        float4 v;
        if constexpr (B16) {
            ushort4 s4 = ((const ushort4*)((const unsigned short*)Sv + (size_t)row * NN))[i];
            v.x = bf2f((short)s4.x); v.y = bf2f((short)s4.y);
            v.z = bf2f((short)s4.z); v.w = bf2f((short)s4.w);
        } else {
            v = ((const float4*)((const float*)Sv + (size_t)row * NN))[i];
        }
        float4 uu = u[i];
        float4 o;
        float p;
        p = __expf(v.x - stt.x) * stt.y;
        o.x = (p >= thr) ? p : ((uu.x >= 0.1f) ? p * (1.0f / 0.9f) : 0.0f);
        p = __expf(v.y - stt.x) * stt.y;
        o.y = (p >= thr) ? p : ((uu.y >= 0.1f) ? p * (1.0f / 0.9f) : 0.0f);
        p = __expf(v.z - stt.x) * stt.y;
        o.z = (p >= thr) ? p : ((uu.z >= 0.1f) ? p * (1.0f / 0.9f) : 0.0f);
        p = __expf(v.w - stt.x) * stt.y;
        o.w = (p >= thr) ? p : ((uu.w >= 0.1f) ? p * (1.0f / 0.9f) : 0.0f);
        o4[i] = o;
    }
}

extern "C" void kernel_launch(void* const* d_in, const int* in_sizes, int n_in,
                              void* d_out, int out_size, void* d_ws, size_t ws_size,
                              hipStream_t stream)
{
    const float* x  = (const float*)d_in[0];
    const float* WQ = (const float*)d_in[1];
    const float* WK = (const float*)d_in[2];
    const float* du = (const float*)d_in[3];
    float* out = (float*)d_out;
    char* ws = (char*)d_ws;

    short* Qh = (short*)(ws + OFF_QH);
    short* Kh = (short*)(ws + OFF_KH);
    float2* stats = (float2*)(ws + OFF_STATS);
    unsigned* hist = (unsigned*)(ws + OFF_H);
    unsigned* gh2  = (unsigned*)(ws + OFF_H2);
    unsigned* st   = (unsigned*)(ws + OFF_ST);

    proj_kernel<<<1024, 256, 0, stream>>>(x, WQ, WK, Qh, Kh);

    const bool b16 = (ws_size >= (size_t)WS_NEED_B16);   // fixed per process -> graph-safe
    if (b16) {
        void* Sb = (void*)(ws + OFF_SB);
        gemm_kernel<true><<<1024, 256, 0, stream>>>(Qh, Kh, Sb);
        histstat_kernel<true><<<256, 512, 0, stream>>>(Sb, stats, hist);
        reduce_kernel<<<8, 1024, 0, stream>>>(hist, gh2);
        scan_kernel<<<1, 1024, 0, stream>>>(gh2, st);
        final_kernel<true><<<NN, 256, 0, stream>>>(Sb, out, (const float4*)du, stats, st);
    } else {
        gemm_kernel<false><<<1024, 256, 0, stream>>>(Qh, Kh, (void*)out);
        histstat_kernel<false><<<256, 512, 0, stream>>>((void*)out, stats, hist);
        reduce_kernel<<<8, 1024, 0, stream>>>(hist, gh2);
        scan_kernel<<<1, 1024, 0, stream>>>(gh2, st);
        final_kernel<false><<<NN, 256, 0, stream>>>((void*)out, out, (const float4*)du, stats, st);
    }
}

// Round 13
// 101.632 us; speedup vs baseline: 3.3093x; 1.3750x over previous
//
#include <hip/hip_runtime.h>
#include <stdint.h>

// Problem constants
#define NN 4096
#define KSEL 1677721u            // int(4096*4096*0.1)
#define INV_SQRT_DK 0.17677669529663687f  // 1/sqrt(32)

// Workspace layout (bytes)
#define OFF_QH 0u                     // bf16 Q [4096][128] = 1 MB
#define OFF_KH (1u<<20)               // bf16 K 1 MB
#define OFF_STATS (2u<<20)            // 4096 * float2 = 32 KB
#define OFF_H   (3u<<20)              // 256 partial hists x 1024 u32 = 1 MB
#define OFF_H2  (4u<<20)              // 8 partial hists = 32 KB
#define OFF_ST  ((4u<<20) + 65536u)   // state
#define OFF_SB  (16u<<20)             // bf16 scores 32 MB (only if ws >= 48MB)
#define WS_NEED_B16 (48u<<20)

#define LDB 104                       // padded k-stride (bf16) -> 52 words, 2-way banks

typedef __attribute__((ext_vector_type(8))) short bf16x8;
typedef __attribute__((ext_vector_type(8))) unsigned short u16x8;
typedef __attribute__((ext_vector_type(4))) float f32x4;

static __device__ __forceinline__ short f2bf(float f) {
    unsigned u = __float_as_uint(f);
    unsigned r = (u + 0x7FFFu + ((u >> 16) & 1u)) >> 16;   // RNE
    return (short)r;
}
static __device__ __forceinline__ float bf2f(short h) {
    return __uint_as_float(((unsigned)(unsigned short)h) << 16);
}

// ---------------------------------------------------------------------------
// 1) Projection via MFMA. Per block: C[64 rows x 64 cols(Q32|K32)] for one b.
//    k reordered k' = f*12 + t (x rows contiguous per f). 8 chunks of 96 k,
//    double-buffered LDS: A = x as bf16 hi+lo (x precision kept), B = W bf16
//    col-major [col][k']. Waves = 4 row-strips of 16; per chunk per wave:
//    3 ksteps x 4 colfrags x {hi,lo} MFMA. Fragment reads are full-width
//    (no broadcast waste -> fixes R11's LDS-issue wall).
//    R12 bug fixed: W-staging Q/K split is at slot 768 (was s>>9 = s/512,
//    which sent WQ slots 512..767 to a NEGATIVE Bl index -> LDS corruption).
// ---------------------------------------------------------------------------
__global__ __launch_bounds__(256) void proj_kernel(
    const float* __restrict__ x, const float* __restrict__ WQ,
    const float* __restrict__ WK,
    short* __restrict__ Qh, short* __restrict__ Kh)
{
    __shared__ short Ah[2][64 * LDB];
    __shared__ short Al[2][64 * LDB];
    __shared__ short Bl[2][64 * LDB];
    const int bx  = blockIdx.x;
    const int b   = bx >> 6;
    const int n0  = (bx & 63) << 6;
    const int tid = threadIdx.x;
    const int l   = tid & 63;
    const int w   = __builtin_amdgcn_readfirstlane(tid >> 6);  // row-strip 0..3
    const int lr  = l & 15;
    const int kg  = (l >> 4) * 8;

    f32x4 acc[4];
#pragma unroll
    for (int j = 0; j < 4; ++j) acc[j] = (f32x4){0.f, 0.f, 0.f, 0.f};

    auto STAGE = [&](int c, int sbuf) {
        // x: 8 f x 64 rows x 3 float4  (1536 slots, 6/thread, coalesced rows)
#pragma unroll
        for (int j = 0; j < 6; ++j) {
            const int s   = tid + (j << 8);
            const int f_l = s / 192;
            const int rem = s - f_l * 192;
            const int r   = rem / 3;
            const int t4  = rem - r * 3;            // 0,1,2 -> t offset 0,4,8
            float4 v = *(const float4*)(x + (size_t)b * 3145728
                                          + (size_t)(c * 8 + f_l) * 49152
                                          + (size_t)(n0 + r) * 12 + t4 * 4);
            const int kl = f_l * 12 + t4 * 4;
            short4 hi, lo;
            hi.x = f2bf(v.x); lo.x = f2bf(v.x - bf2f(hi.x));
            hi.y = f2bf(v.y); lo.y = f2bf(v.y - bf2f(hi.y));
            hi.z = f2bf(v.z); lo.z = f2bf(v.z - bf2f(hi.z));
            hi.w = f2bf(v.w); lo.w = f2bf(v.w - bf2f(hi.w));
            *(short4*)&Ah[sbuf][r * LDB + kl] = hi;
            *(short4*)&Al[sbuf][r * LDB + kl] = lo;
        }
        // W: 2 mats x 96 k x 8 col4 (1536 slots, 6/thread). B col-major [col][k'].
#pragma unroll
        for (int j = 0; j < 6; ++j) {
            const int s   = tid + (j << 8);
            const int qk  = (s >= 768) ? 1 : 0;      // FIXED: split at 768, not 512
            const int rem = s - qk * 768;
            const int kr  = rem >> 3;                // 0..95
            const int c4  = rem & 7;
            const int t   = kr % 12;
            const int f_l = kr / 12;
            const float* __restrict__ Wp = qk ? WK : WQ;
            float4 wv = *(const float4*)(Wp + (size_t)(t * 64 + c * 8 + f_l) * 32 + (c4 << 2));
            const int kl = f_l * 12 + t;
            const int col = (qk << 5) + (c4 << 2);
            Bl[sbuf][(col + 0) * LDB + kl] = f2bf(wv.x);
            Bl[sbuf][(col + 1) * LDB + kl] = f2bf(wv.y);
            Bl[sbuf][(col + 2) * LDB + kl] = f2bf(wv.z);
            Bl[sbuf][(col + 3) * LDB + kl] = f2bf(wv.w);
        }
    };

    STAGE(0, 0);
    int buf = 0;
    for (int c = 0; c < 8; ++c) {
        __syncthreads();
        if (c < 7) STAGE(c + 1, buf ^ 1);
#pragma unroll
        for (int ks = 0; ks < 3; ++ks) {
            const int ko = ks * 32 + kg;
            bf16x8 ah = *(const bf16x8*)&Ah[buf][(w * 16 + lr) * LDB + ko];
            bf16x8 al = *(const bf16x8*)&Al[buf][(w * 16 + lr) * LDB + ko];
#pragma unroll
            for (int j = 0; j < 4; ++j) {
                bf16x8 bb = *(const bf16x8*)&Bl[buf][(j * 16 + lr) * LDB + ko];
                acc[j] = __builtin_amdgcn_mfma_f32_16x16x32_bf16(ah, bb, acc[j], 0, 0, 0);
                acc[j] = __builtin_amdgcn_mfma_f32_16x16x32_bf16(al, bb, acc[j], 0, 0, 0);
            }
        }
        buf ^= 1;
    }

    // C/D mapping (m89-verified): col = lane&15, row = (lane>>4)*4 + reg
#pragma unroll
    for (int j = 0; j < 4; ++j) {
        const int col = j * 16 + lr;
#pragma unroll
        for (int r = 0; r < 4; ++r) {
            const int row = n0 + w * 16 + (l >> 4) * 4 + r;
            if (col < 32)
                Qh[(size_t)row * 128 + (b << 5) + col] = f2bf(acc[j][r] * INV_SQRT_DK);
            else
                Kh[(size_t)row * 128 + (b << 5) + (col - 32)] = f2bf(acc[j][r]);
        }
    }
}

// ---------------------------------------------------------------------------
// 2) S = Q @ K^T via MFMA 16x16x32 bf16. 128x128 tile per 256-thread block,
//    wave tile 64x64 (4x4 frags), 2-deep register ping-pong prefetch.
// ---------------------------------------------------------------------------
template<bool B16>
__global__ __launch_bounds__(256, 3) void gemm_kernel(
    const short* __restrict__ Qh, const short* __restrict__ Kh, void* Sv)
{
    const int bi = blockIdx.x >> 5, bj = blockIdx.x & 31;
    const int tid = threadIdx.x;
    const int w = tid >> 6, l = tid & 63;
    const int m0 = bi * 128 + (w >> 1) * 64;
    const int n0 = bj * 128 + (w & 1) * 64;
    const int lr = l & 15;
    const int kg = (l >> 4) * 8;

    f32x4 acc[4][4];
#pragma unroll
    for (int i = 0; i < 4; ++i)
#pragma unroll
        for (int j = 0; j < 4; ++j) acc[i][j] = (f32x4){0.f, 0.f, 0.f, 0.f};

    bf16x8 aA[4], bA[4], aB[4], bB[4];

    auto LD = [&](bf16x8* A, bf16x8* B, int k0) {
#pragma unroll
        for (int i = 0; i < 4; ++i) {
            A[i] = *(const bf16x8*)(Qh + (size_t)(m0 + i * 16 + lr) * 128 + k0 + kg);
            B[i] = *(const bf16x8*)(Kh + (size_t)(n0 + i * 16 + lr) * 128 + k0 + kg);
        }
    };
    auto DOMFMA = [&](bf16x8* A, bf16x8* B) {
#pragma unroll
        for (int i = 0; i < 4; ++i)
#pragma unroll
            for (int j = 0; j < 4; ++j)
                acc[i][j] = __builtin_amdgcn_mfma_f32_16x16x32_bf16(A[i], B[j], acc[i][j], 0, 0, 0);
    };

    LD(aA, bA, 0);
    LD(aB, bB, 32);
    DOMFMA(aA, bA);  LD(aA, bA, 64);
    DOMFMA(aB, bB);  LD(aB, bB, 96);
    DOMFMA(aA, bA);
    DOMFMA(aB, bB);

    // C/D mapping (m89-verified): col = lane&15, row = (lane>>4)*4 + reg
#pragma unroll
    for (int i = 0; i < 4; ++i) {
        int rowb = m0 + i * 16 + (l >> 4) * 4;
#pragma unroll
        for (int j = 0; j < 4; ++j) {
            int col = n0 + j * 16 + (l & 15);
#pragma unroll
            for (int r = 0; r < 4; ++r) {
                if constexpr (B16)
                    ((unsigned short*)Sv)[(size_t)(rowb + r) * NN + col] =
                        (unsigned short)f2bf(acc[i][j][r]);
                else
                    ((float*)Sv)[(size_t)(rowb + r) * NN + col] = acc[i][j][r];
            }
        }
    }
}

// ---------------------------------------------------------------------------
// 3) Fused row stats + histogram. One wave per row, row in registers.
//    Each block OWNS partial-hist slot blockIdx.x (full overwrite, no memset).
// ---------------------------------------------------------------------------
template<bool B16>
__global__ __launch_bounds__(512) void histstat_kernel(
    const void* __restrict__ Sv, float2* __restrict__ stats,
    unsigned* __restrict__ gh)
{
    __shared__ unsigned h[1024];
    const int tid = threadIdx.x;
    const int l = tid & 63;
    const int w = tid >> 6;

    for (int i = tid; i < 1024; i += 512) h[i] = 0;
    __syncthreads();

#pragma unroll
    for (int r = 0; r < 2; ++r) {
        const int row = (blockIdx.x << 4) + (r << 3) + w;

        float v[64];
        if constexpr (B16) {
            const u16x8* rp = (const u16x8*)((const unsigned short*)Sv + (size_t)row * NN);
#pragma unroll
            for (int j = 0; j < 8; ++j) {
                u16x8 e = rp[l + (j << 6)];
#pragma unroll
                for (int i = 0; i < 8; ++i) v[j * 8 + i] = bf2f((short)e[i]);
            }
        } else {
            const float4* rp = (const float4*)((const float*)Sv + (size_t)row * NN);
#pragma unroll
            for (int j = 0; j < 16; ++j) {
                float4 t = rp[l + (j << 6)];
                v[j * 4 + 0] = t.x; v[j * 4 + 1] = t.y;
                v[j * 4 + 2] = t.z; v[j * 4 + 3] = t.w;
            }
        }

        float m = -3.4e38f;
#pragma unroll
        for (int j = 0; j < 64; ++j) m = fmaxf(m, v[j]);
#pragma unroll
        for (int off = 32; off; off >>= 1) m = fmaxf(m, __shfl_xor(m, off));

        float s = 0.f;
#pragma unroll
        for (int j = 0; j < 64; ++j) { v[j] = __expf(v[j] - m); s += v[j]; }
#pragma unroll
        for (int off = 32; off; off >>= 1) s += __shfl_xor(s, off);
        const float inv = 1.0f / s;
        if (l == 0) stats[row] = make_float2(m, inv);

#pragma unroll
        for (int j = 0; j < 64; ++j) {
            int b0 = min(max((int)(__float_as_uint(v[j] * inv) >> 16) - 0x3780, 0), 1023);
            atomicAdd(&h[b0], 1u);
        }
    }

    __syncthreads();
    unsigned* dst = gh + ((unsigned)blockIdx.x << 10);
    for (int i = tid; i < 1024; i += 512) dst[i] = h[i];   // full overwrite
}

// ---------------------------------------------------------------------------
// 4a) Pre-reduce 256 partials -> 8.   4b) Final reduce + suffix-scan.
// ---------------------------------------------------------------------------
__global__ __launch_bounds__(1024) void reduce_kernel(
    const unsigned* __restrict__ gh, unsigned* __restrict__ gh2)
{
    const int t = threadIdx.x, b = blockIdx.x;
    unsigned s = 0;
    for (int p = 0; p < 32; ++p) s += gh[((unsigned)(b * 32 + p) << 10) + t];
    gh2[((unsigned)b << 10) + t] = s;
}

__global__ __launch_bounds__(1024) void scan_kernel(
    const unsigned* __restrict__ gh2, unsigned* st)
{
    __shared__ unsigned P[1024];
    const int t = threadIdx.x;
    unsigned s = 0;
#pragma unroll
    for (int p = 0; p < 8; ++p) s += gh2[(p << 10) + t];
    P[t] = s;
    __syncthreads();
    for (int off = 1; off < 1024; off <<= 1) {
        unsigned v = P[t] + ((t + off < 1024) ? P[t + off] : 0u);
        __syncthreads();
        P[t] = v;
        __syncthreads();
    }
    if (P[t] >= KSEL && (t == 1023 || P[t + 1] < KSEL))
        st[2] = (0x3780u + (unsigned)t) << 16;   // lower edge of selected bin
}

// ---------------------------------------------------------------------------
// 5) Final: recompute p, threshold -> keep; else dropout (x1/0.9 or 0).
// ---------------------------------------------------------------------------
template<bool B16>
__global__ __launch_bounds__(256) void final_kernel(
    const void* __restrict__ Sv, float* __restrict__ out,
    const float4* __restrict__ u4,
    const float2* __restrict__ stats, const unsigned* __restrict__ st)
{
    const int row = blockIdx.x;
    const float thr = __uint_as_float(st[2]);
    const float2 stt = stats[row];
    float4* o4 = (float4*)(out + (size_t)row * NN);
    const float4* u = u4 + (size_t)row * 1024;
    for (int i = threadIdx.x; i < 1024; i += 256) {
        float4 v;
        if constexpr (B16) {
            ushort4 s4 = ((const ushort4*)((const unsigned short*)Sv + (size_t)row * NN))[i];
            v.x = bf2f((short)s4.x); v.y = bf2f((short)s4.y);
            v.z = bf2f((short)s4.z); v.w = bf2f((short)s4.w);
        } else {
            v = ((const float4*)((const float*)Sv + (size_t)row * NN))[i];
        }
        float4 uu = u[i];
        float4 o;
        float p;
        p = __expf(v.x - stt.x) * stt.y;
        o.x = (p >= thr) ? p : ((uu.x >= 0.1f) ? p * (1.0f / 0.9f) : 0.0f);
        p = __expf(v.y - stt.x) * stt.y;
        o.y = (p >= thr) ? p : ((uu.y >= 0.1f) ? p * (1.0f / 0.9f) : 0.0f);
        p = __expf(v.z - stt.x) * stt.y;
        o.z = (p >= thr) ? p : ((uu.z >= 0.1f) ? p * (1.0f / 0.9f) : 0.0f);
        p = __expf(v.w - stt.x) * stt.y;
        o.w = (p >= thr) ? p : ((uu.w >= 0.1f) ? p * (1.0f / 0.9f) : 0.0f);
        o4[i] = o;
    }
}

extern "C" void kernel_launch(void* const* d_in, const int* in_sizes, int n_in,
                              void* d_out, int out_size, void* d_ws, size_t ws_size,
                              hipStream_t stream)
{
    const float* x  = (const float*)d_in[0];
    const float* WQ = (const float*)d_in[1];
    const float* WK = (const float*)d_in[2];
    const float* du = (const float*)d_in[3];
    float* out = (float*)d_out;
    char* ws = (char*)d_ws;

    short* Qh = (short*)(ws + OFF_QH);
    short* Kh = (short*)(ws + OFF_KH);
    float2* stats = (float2*)(ws + OFF_STATS);
    unsigned* hist = (unsigned*)(ws + OFF_H);
    unsigned* gh2  = (unsigned*)(ws + OFF_H2);
    unsigned* st   = (unsigned*)(ws + OFF_ST);

    proj_kernel<<<256, 256, 0, stream>>>(x, WQ, WK, Qh, Kh);

    const bool b16 = (ws_size >= (size_t)WS_NEED_B16);   // fixed per process -> graph-safe
    if (b16) {
        void* Sb = (void*)(ws + OFF_SB);
        gemm_kernel<true><<<1024, 256, 0, stream>>>(Qh, Kh, Sb);
        histstat_kernel<true><<<256, 512, 0, stream>>>(Sb, stats, hist);
        reduce_kernel<<<8, 1024, 0, stream>>>(hist, gh2);
        scan_kernel<<<1, 1024, 0, stream>>>(gh2, st);
        final_kernel<true><<<NN, 256, 0, stream>>>(Sb, out, (const float4*)du, stats, st);
    } else {
        gemm_kernel<false><<<1024, 256, 0, stream>>>(Qh, Kh, (void*)out);
        histstat_kernel<false><<<256, 512, 0, stream>>>((void*)out, stats, hist);
        reduce_kernel<<<8, 1024, 0, stream>>>(hist, gh2);
        scan_kernel<<<1, 1024, 0, stream>>>(gh2, st);
        final_kernel<false><<<NN, 256, 0, stream>>>((void*)out, out, (const float4*)du, stats, st);
    }
}

// Round 14
// 100.795 us; speedup vs baseline: 3.3368x; 1.0083x over previous
//
#include <hip/hip_runtime.h>
#include <stdint.h>

// Problem constants
#define NN 4096
#define KSEL 1677721u            // int(4096*4096*0.1)
#define INV_SQRT_DK 0.17677669529663687f  // 1/sqrt(32)

// Workspace layout (bytes)
#define OFF_QH 0u                     // bf16 Q [4096][128] = 1 MB
#define OFF_KH (1u<<20)               // bf16 K 1 MB
#define OFF_STATS (2u<<20)            // 4096 * float2 = 32 KB
#define OFF_H   (3u<<20)              // 256 partial hists x 1024 u32 = 1 MB
#define OFF_H2  (4u<<20)              // 8 partial hists = 32 KB
#define OFF_ST  ((4u<<20) + 65536u)   // state
#define OFF_SB  (16u<<20)             // bf16 scores 32 MB (only if ws >= 48MB)
#define WS_NEED_B16 (48u<<20)

#define LDB 104                       // padded k-stride (bf16) -> 52 words, 2-way banks

typedef __attribute__((ext_vector_type(8))) short bf16x8;
typedef __attribute__((ext_vector_type(8))) unsigned short u16x8;
typedef __attribute__((ext_vector_type(4))) float f32x4;

static __device__ __forceinline__ short f2bf(float f) {
    unsigned u = __float_as_uint(f);
    unsigned r = (u + 0x7FFFu + ((u >> 16) & 1u)) >> 16;   // RNE
    return (short)r;
}
static __device__ __forceinline__ float bf2f(short h) {
    return __uint_as_float(((unsigned)(unsigned short)h) << 16);
}

// ---------------------------------------------------------------------------
// 1) Projection via MFMA. Per block: C[64 rows x 64 cols(Q32|K32)] for one b.
//    k reordered k' = f*12 + t. 8 chunks of 96 k, double-buffered LDS:
//    A = x as bf16 hi+lo, B = W bf16 col-major [col][k'].
// ---------------------------------------------------------------------------
__global__ __launch_bounds__(256) void proj_kernel(
    const float* __restrict__ x, const float* __restrict__ WQ,
    const float* __restrict__ WK,
    short* __restrict__ Qh, short* __restrict__ Kh)
{
    __shared__ short Ah[2][64 * LDB];
    __shared__ short Al[2][64 * LDB];
    __shared__ short Bl[2][64 * LDB];
    const int bx  = blockIdx.x;
    const int b   = bx >> 6;
    const int n0  = (bx & 63) << 6;
    const int tid = threadIdx.x;
    const int l   = tid & 63;
    const int w   = __builtin_amdgcn_readfirstlane(tid >> 6);  // row-strip 0..3
    const int lr  = l & 15;
    const int kg  = (l >> 4) * 8;

    f32x4 acc[4];
#pragma unroll
    for (int j = 0; j < 4; ++j) acc[j] = (f32x4){0.f, 0.f, 0.f, 0.f};

    auto STAGE = [&](int c, int sbuf) {
        // x: 8 f x 64 rows x 3 float4  (1536 slots, 6/thread, coalesced rows)
#pragma unroll
        for (int j = 0; j < 6; ++j) {
            const int s   = tid + (j << 8);
            const int f_l = s / 192;
            const int rem = s - f_l * 192;
            const int r   = rem / 3;
            const int t4  = rem - r * 3;            // 0,1,2 -> t offset 0,4,8
            float4 v = *(const float4*)(x + (size_t)b * 3145728
                                          + (size_t)(c * 8 + f_l) * 49152
                                          + (size_t)(n0 + r) * 12 + t4 * 4);
            const int kl = f_l * 12 + t4 * 4;
            short4 hi, lo;
            hi.x = f2bf(v.x); lo.x = f2bf(v.x - bf2f(hi.x));
            hi.y = f2bf(v.y); lo.y = f2bf(v.y - bf2f(hi.y));
            hi.z = f2bf(v.z); lo.z = f2bf(v.z - bf2f(hi.z));
            hi.w = f2bf(v.w); lo.w = f2bf(v.w - bf2f(hi.w));
            *(short4*)&Ah[sbuf][r * LDB + kl] = hi;
            *(short4*)&Al[sbuf][r * LDB + kl] = lo;
        }
        // W: 2 mats x 96 k x 8 col4 (1536 slots, 6/thread). B col-major [col][k'].
#pragma unroll
        for (int j = 0; j < 6; ++j) {
            const int s   = tid + (j << 8);
            const int qk  = (s >= 768) ? 1 : 0;      // split at 768
            const int rem = s - qk * 768;
            const int kr  = rem >> 3;                // 0..95
            const int c4  = rem & 7;
            const int t   = kr % 12;
            const int f_l = kr / 12;
            const float* __restrict__ Wp = qk ? WK : WQ;
            float4 wv = *(const float4*)(Wp + (size_t)(t * 64 + c * 8 + f_l) * 32 + (c4 << 2));
            const int kl = f_l * 12 + t;
            const int col = (qk << 5) + (c4 << 2);
            Bl[sbuf][(col + 0) * LDB + kl] = f2bf(wv.x);
            Bl[sbuf][(col + 1) * LDB + kl] = f2bf(wv.y);
            Bl[sbuf][(col + 2) * LDB + kl] = f2bf(wv.z);
            Bl[sbuf][(col + 3) * LDB + kl] = f2bf(wv.w);
        }
    };

    STAGE(0, 0);
    int buf = 0;
    for (int c = 0; c < 8; ++c) {
        __syncthreads();
        if (c < 7) STAGE(c + 1, buf ^ 1);
#pragma unroll
        for (int ks = 0; ks < 3; ++ks) {
            const int ko = ks * 32 + kg;
            bf16x8 ah = *(const bf16x8*)&Ah[buf][(w * 16 + lr) * LDB + ko];
            bf16x8 al = *(const bf16x8*)&Al[buf][(w * 16 + lr) * LDB + ko];
#pragma unroll
            for (int j = 0; j < 4; ++j) {
                bf16x8 bb = *(const bf16x8*)&Bl[buf][(j * 16 + lr) * LDB + ko];
                acc[j] = __builtin_amdgcn_mfma_f32_16x16x32_bf16(ah, bb, acc[j], 0, 0, 0);
                acc[j] = __builtin_amdgcn_mfma_f32_16x16x32_bf16(al, bb, acc[j], 0, 0, 0);
            }
        }
        buf ^= 1;
    }

    // C/D mapping (m89-verified): col = lane&15, row = (lane>>4)*4 + reg
#pragma unroll
    for (int j = 0; j < 4; ++j) {
        const int col = j * 16 + lr;
#pragma unroll
        for (int r = 0; r < 4; ++r) {
            const int row = n0 + w * 16 + (l >> 4) * 4 + r;
            if (col < 32)
                Qh[(size_t)row * 128 + (b << 5) + col] = f2bf(acc[j][r] * INV_SQRT_DK);
            else
                Kh[(size_t)row * 128 + (b << 5) + (col - 32)] = f2bf(acc[j][r]);
        }
    }
}

// ---------------------------------------------------------------------------
// 2) S = Q @ K^T via MFMA 16x16x32 bf16. 128x128 tile per 256-thread block,
//    wave tile 64x64 (4x4 frags), 2-deep register ping-pong prefetch.
// ---------------------------------------------------------------------------
template<bool B16>
__global__ __launch_bounds__(256, 3) void gemm_kernel(
    const short* __restrict__ Qh, const short* __restrict__ Kh, void* Sv)
{
    const int bi = blockIdx.x >> 5, bj = blockIdx.x & 31;
    const int tid = threadIdx.x;
    const int w = tid >> 6, l = tid & 63;
    const int m0 = bi * 128 + (w >> 1) * 64;
    const int n0 = bj * 128 + (w & 1) * 64;
    const int lr = l & 15;
    const int kg = (l >> 4) * 8;

    f32x4 acc[4][4];
#pragma unroll
    for (int i = 0; i < 4; ++i)
#pragma unroll
        for (int j = 0; j < 4; ++j) acc[i][j] = (f32x4){0.f, 0.f, 0.f, 0.f};

    bf16x8 aA[4], bA[4], aB[4], bB[4];

    auto LD = [&](bf16x8* A, bf16x8* B, int k0) {
#pragma unroll
        for (int i = 0; i < 4; ++i) {
            A[i] = *(const bf16x8*)(Qh + (size_t)(m0 + i * 16 + lr) * 128 + k0 + kg);
            B[i] = *(const bf16x8*)(Kh + (size_t)(n0 + i * 16 + lr) * 128 + k0 + kg);
        }
    };
    auto DOMFMA = [&](bf16x8* A, bf16x8* B) {
#pragma unroll
        for (int i = 0; i < 4; ++i)
#pragma unroll
            for (int j = 0; j < 4; ++j)
                acc[i][j] = __builtin_amdgcn_mfma_f32_16x16x32_bf16(A[i], B[j], acc[i][j], 0, 0, 0);
    };

    LD(aA, bA, 0);
    LD(aB, bB, 32);
    DOMFMA(aA, bA);  LD(aA, bA, 64);
    DOMFMA(aB, bB);  LD(aB, bB, 96);
    DOMFMA(aA, bA);
    DOMFMA(aB, bB);

    // C/D mapping (m89-verified): col = lane&15, row = (lane>>4)*4 + reg
#pragma unroll
    for (int i = 0; i < 4; ++i) {
        int rowb = m0 + i * 16 + (l >> 4) * 4;
#pragma unroll
        for (int j = 0; j < 4; ++j) {
            int col = n0 + j * 16 + (l & 15);
#pragma unroll
            for (int r = 0; r < 4; ++r) {
                if constexpr (B16)
                    ((unsigned short*)Sv)[(size_t)(rowb + r) * NN + col] =
                        (unsigned short)f2bf(acc[i][j][r]);
                else
                    ((float*)Sv)[(size_t)(rowb + r) * NN + col] = acc[i][j][r];
            }
        }
    }
}

// ---------------------------------------------------------------------------
// 3) Fused row stats + histogram. One wave per row, row in registers.
//    Each block OWNS partial-hist slot blockIdx.x (full overwrite, no memset).
// ---------------------------------------------------------------------------
template<bool B16>
__global__ __launch_bounds__(512) void histstat_kernel(
    const void* __restrict__ Sv, float2* __restrict__ stats,
    unsigned* __restrict__ gh)
{
    __shared__ unsigned h[1024];
    const int tid = threadIdx.x;
    const int l = tid & 63;
    const int w = tid >> 6;

    for (int i = tid; i < 1024; i += 512) h[i] = 0;
    __syncthreads();

#pragma unroll
    for (int r = 0; r < 2; ++r) {
        const int row = (blockIdx.x << 4) + (r << 3) + w;

        float v[64];
        if constexpr (B16) {
            const u16x8* rp = (const u16x8*)((const unsigned short*)Sv + (size_t)row * NN);
#pragma unroll
            for (int j = 0; j < 8; ++j) {
                u16x8 e = rp[l + (j << 6)];
#pragma unroll
                for (int i = 0; i < 8; ++i) v[j * 8 + i] = bf2f((short)e[i]);
            }
        } else {
            const float4* rp = (const float4*)((const float*)Sv + (size_t)row * NN);
#pragma unroll
            for (int j = 0; j < 16; ++j) {
                float4 t = rp[l + (j << 6)];
                v[j * 4 + 0] = t.x; v[j * 4 + 1] = t.y;
                v[j * 4 + 2] = t.z; v[j * 4 + 3] = t.w;
            }
        }

        float m = -3.4e38f;
#pragma unroll
        for (int j = 0; j < 64; ++j) m = fmaxf(m, v[j]);
#pragma unroll
        for (int off = 32; off; off >>= 1) m = fmaxf(m, __shfl_xor(m, off));

        float s = 0.f;
#pragma unroll
        for (int j = 0; j < 64; ++j) { v[j] = __expf(v[j] - m); s += v[j]; }
#pragma unroll
        for (int off = 32; off; off >>= 1) s += __shfl_xor(s, off);
        const float inv = 1.0f / s;
        if (l == 0) stats[row] = make_float2(m, inv);

#pragma unroll
        for (int j = 0; j < 64; ++j) {
            int b0 = min(max((int)(__float_as_uint(v[j] * inv) >> 16) - 0x3780, 0), 1023);
            atomicAdd(&h[b0], 1u);
        }
    }

    __syncthreads();
    unsigned* dst = gh + ((unsigned)blockIdx.x << 10);
    for (int i = tid; i < 1024; i += 512) dst[i] = h[i];   // full overwrite
}

// ---------------------------------------------------------------------------
// 4a) Pre-reduce 256 partials -> 8.   4b) Final reduce + suffix-scan.
// ---------------------------------------------------------------------------
__global__ __launch_bounds__(1024) void reduce_kernel(
    const unsigned* __restrict__ gh, unsigned* __restrict__ gh2)
{
    const int t = threadIdx.x, b = blockIdx.x;
    unsigned s = 0;
    for (int p = 0; p < 32; ++p) s += gh[((unsigned)(b * 32 + p) << 10) + t];
    gh2[((unsigned)b << 10) + t] = s;
}

__global__ __launch_bounds__(1024) void scan_kernel(
    const unsigned* __restrict__ gh2, unsigned* st)
{
    __shared__ unsigned P[1024];
    const int t = threadIdx.x;
    unsigned s = 0;
#pragma unroll
    for (int p = 0; p < 8; ++p) s += gh2[(p << 10) + t];
    P[t] = s;
    __syncthreads();
    for (int off = 1; off < 1024; off <<= 1) {
        unsigned v = P[t] + ((t + off < 1024) ? P[t + off] : 0u);
        __syncthreads();
        P[t] = v;
        __syncthreads();
    }
    if (P[t] >= KSEL && (t == 1023 || P[t + 1] < KSEL))
        st[2] = (0x3780u + (unsigned)t) << 16;   // lower edge of selected bin
}

// ---------------------------------------------------------------------------
// 5) Final: recompute p, threshold -> keep; else dropout (x1/0.9 or 0).
//    ALL 8 loads issued up front (96 B in flight/thread) before any compute:
//    R13 showed 39us @ 3.0 TB/s with only 24 B in flight -> latency-bound.
// ---------------------------------------------------------------------------
template<bool B16>
__global__ __launch_bounds__(256) void final_kernel(
    const void* __restrict__ Sv, float* __restrict__ out,
    const float4* __restrict__ u4,
    const float2* __restrict__ stats, const unsigned* __restrict__ st)
{
    const int row = blockIdx.x;
    const int tid = threadIdx.x;
    const float thr = __uint_as_float(st[2]);
    const float2 stt = stats[row];
    float4* o4 = (float4*)(out + (size_t)row * NN);
    const float4* u = u4 + (size_t)row * 1024;

    float4 sv[4];       // scores as fp32
    float4 uv[4];

    if constexpr (B16) {
        const ushort4* S4 = (const ushort4*)((const unsigned short*)Sv + (size_t)row * NN);
        ushort4 sraw[4];
#pragma unroll
        for (int j = 0; j < 4; ++j) sraw[j] = S4[tid + (j << 8)];
#pragma unroll
        for (int j = 0; j < 4; ++j) uv[j] = u[tid + (j << 8)];
#pragma unroll
        for (int j = 0; j < 4; ++j) {
            sv[j].x = bf2f((short)sraw[j].x); sv[j].y = bf2f((short)sraw[j].y);
            sv[j].z = bf2f((short)sraw[j].z); sv[j].w = bf2f((short)sraw[j].w);
        }
    } else {
        const float4* S4 = (const float4*)((const float*)Sv + (size_t)row * NN);
#pragma unroll
        for (int j = 0; j < 4; ++j) sv[j] = S4[tid + (j << 8)];
#pragma unroll
        for (int j = 0; j < 4; ++j) uv[j] = u[tid + (j << 8)];
    }

#pragma unroll
    for (int j = 0; j < 4; ++j) {
        float4 o;
        float p;
        p = __expf(sv[j].x - stt.x) * stt.y;
        o.x = (p >= thr) ? p : ((uv[j].x >= 0.1f) ? p * (1.0f / 0.9f) : 0.0f);
        p = __expf(sv[j].y - stt.x) * stt.y;
        o.y = (p >= thr) ? p : ((uv[j].y >= 0.1f) ? p * (1.0f / 0.9f) : 0.0f);
        p = __expf(sv[j].z - stt.x) * stt.y;
        o.z = (p >= thr) ? p : ((uv[j].z >= 0.1f) ? p * (1.0f / 0.9f) : 0.0f);
        p = __expf(sv[j].w - stt.x) * stt.y;
        o.w = (p >= thr) ? p : ((uv[j].w >= 0.1f) ? p * (1.0f / 0.9f) : 0.0f);
        o4[tid + (j << 8)] = o;
    }
}

extern "C" void kernel_launch(void* const* d_in, const int* in_sizes, int n_in,
                              void* d_out, int out_size, void* d_ws, size_t ws_size,
                              hipStream_t stream)
{
    const float* x  = (const float*)d_in[0];
    const float* WQ = (const float*)d_in[1];
    const float* WK = (const float*)d_in[2];
    const float* du = (const float*)d_in[3];
    float* out = (float*)d_out;
    char* ws = (char*)d_ws;

    short* Qh = (short*)(ws + OFF_QH);
    short* Kh = (short*)(ws + OFF_KH);
    float2* stats = (float2*)(ws + OFF_STATS);
    unsigned* hist = (unsigned*)(ws + OFF_H);
    unsigned* gh2  = (unsigned*)(ws + OFF_H2);
    unsigned* st   = (unsigned*)(ws + OFF_ST);

    proj_kernel<<<256, 256, 0, stream>>>(x, WQ, WK, Qh, Kh);

    const bool b16 = (ws_size >= (size_t)WS_NEED_B16);   // fixed per process -> graph-safe
    if (b16) {
        void* Sb = (void*)(ws + OFF_SB);
        gemm_kernel<true><<<1024, 256, 0, stream>>>(Qh, Kh, Sb);
        histstat_kernel<true><<<256, 512, 0, stream>>>(Sb, stats, hist);
        reduce_kernel<<<8, 1024, 0, stream>>>(hist, gh2);
        scan_kernel<<<1, 1024, 0, stream>>>(gh2, st);
        final_kernel<true><<<NN, 256, 0, stream>>>(Sb, out, (const float4*)du, stats, st);
    } else {
        gemm_kernel<false><<<1024, 256, 0, stream>>>(Qh, Kh, (void*)out);
        histstat_kernel<false><<<256, 512, 0, stream>>>((void*)out, stats, hist);
        reduce_kernel<<<8, 1024, 0, stream>>>(hist, gh2);
        scan_kernel<<<1, 1024, 0, stream>>>(gh2, st);
        final_kernel<false><<<NN, 256, 0, stream>>>((void*)out, out, (const float4*)du, stats, st);
    }
}

// Round 15
// 83.181 us; speedup vs baseline: 4.0433x; 1.2118x over previous
//
#include <hip/hip_runtime.h>
#include <stdint.h>

// Problem constants
#define NN 4096
#define KSEL_S 419430u           // int(4096*4096*0.1) / 4 (4x-subsampled histogram)
#define INV_SQRT_DK 0.17677669529663687f  // 1/sqrt(32)

// Workspace layout (bytes)
#define OFF_QH 0u                     // bf16 Q [4096][128] = 1 MB
#define OFF_KH (1u<<20)               // bf16 K 1 MB
#define OFF_STATS (2u<<20)            // 4096 * float2 = 32 KB
#define OFF_H   (3u<<20)              // 256 partial hists x 1024 u32 = 1 MB
#define OFF_H2  (4u<<20)              // 8 partial hists = 32 KB
#define OFF_ST  ((4u<<20) + 65536u)   // state
#define OFF_MASK (5u<<20)             // dropout bitmask 4096x512B = 2 MB
#define OFF_SB  (16u<<20)             // bf16 scores 32 MB (only if ws >= 48MB)
#define WS_NEED_B16 (48u<<20)

#define LDB 104                       // padded k-stride (bf16) -> 52 words, 2-way banks

typedef __attribute__((ext_vector_type(8))) short bf16x8;
typedef __attribute__((ext_vector_type(8))) unsigned short u16x8;
typedef __attribute__((ext_vector_type(4))) float f32x4;

static __device__ __forceinline__ short f2bf(float f) {
    unsigned u = __float_as_uint(f);
    unsigned r = (u + 0x7FFFu + ((u >> 16) & 1u)) >> 16;   // RNE
    return (short)r;
}
static __device__ __forceinline__ float bf2f(short h) {
    return __uint_as_float(((unsigned)(unsigned short)h) << 16);
}

// ---------------------------------------------------------------------------
// 1) Projection via MFMA. Per block: C[64 rows x 64 cols(Q32|K32)] for one b.
//    k reordered k' = f*12 + t. 8 chunks of 96 k, double-buffered LDS:
//    A = x as bf16 hi+lo, B = W bf16 col-major [col][k'].
// ---------------------------------------------------------------------------
__global__ __launch_bounds__(256) void proj_kernel(
    const float* __restrict__ x, const float* __restrict__ WQ,
    const float* __restrict__ WK,
    short* __restrict__ Qh, short* __restrict__ Kh)
{
    __shared__ short Ah[2][64 * LDB];
    __shared__ short Al[2][64 * LDB];
    __shared__ short Bl[2][64 * LDB];
    const int bx  = blockIdx.x;
    const int b   = bx >> 6;
    const int n0  = (bx & 63) << 6;
    const int tid = threadIdx.x;
    const int l   = tid & 63;
    const int w   = __builtin_amdgcn_readfirstlane(tid >> 6);  // row-strip 0..3
    const int lr  = l & 15;
    const int kg  = (l >> 4) * 8;

    f32x4 acc[4];
#pragma unroll
    for (int j = 0; j < 4; ++j) acc[j] = (f32x4){0.f, 0.f, 0.f, 0.f};

    auto STAGE = [&](int c, int sbuf) {
        // x: 8 f x 64 rows x 3 float4  (1536 slots, 6/thread, coalesced rows)
#pragma unroll
        for (int j = 0; j < 6; ++j) {
            const int s   = tid + (j << 8);
            const int f_l = s / 192;
            const int rem = s - f_l * 192;
            const int r   = rem / 3;
            const int t4  = rem - r * 3;            // 0,1,2 -> t offset 0,4,8
            float4 v = *(const float4*)(x + (size_t)b * 3145728
                                          + (size_t)(c * 8 + f_l) * 49152
                                          + (size_t)(n0 + r) * 12 + t4 * 4);
            const int kl = f_l * 12 + t4 * 4;
            short4 hi, lo;
            hi.x = f2bf(v.x); lo.x = f2bf(v.x - bf2f(hi.x));
            hi.y = f2bf(v.y); lo.y = f2bf(v.y - bf2f(hi.y));
            hi.z = f2bf(v.z); lo.z = f2bf(v.z - bf2f(hi.z));
            hi.w = f2bf(v.w); lo.w = f2bf(v.w - bf2f(hi.w));
            *(short4*)&Ah[sbuf][r * LDB + kl] = hi;
            *(short4*)&Al[sbuf][r * LDB + kl] = lo;
        }
        // W: 2 mats x 96 k x 8 col4 (1536 slots, 6/thread). B col-major [col][k'].
#pragma unroll
        for (int j = 0; j < 6; ++j) {
            const int s   = tid + (j << 8);
            const int qk  = (s >= 768) ? 1 : 0;      // split at 768
            const int rem = s - qk * 768;
            const int kr  = rem >> 3;                // 0..95
            const int c4  = rem & 7;
            const int t   = kr % 12;
            const int f_l = kr / 12;
            const float* __restrict__ Wp = qk ? WK : WQ;
            float4 wv = *(const float4*)(Wp + (size_t)(t * 64 + c * 8 + f_l) * 32 + (c4 << 2));
            const int kl = f_l * 12 + t;
            const int col = (qk << 5) + (c4 << 2);
            Bl[sbuf][(col + 0) * LDB + kl] = f2bf(wv.x);
            Bl[sbuf][(col + 1) * LDB + kl] = f2bf(wv.y);
            Bl[sbuf][(col + 2) * LDB + kl] = f2bf(wv.z);
            Bl[sbuf][(col + 3) * LDB + kl] = f2bf(wv.w);
        }
    };

    STAGE(0, 0);
    int buf = 0;
    for (int c = 0; c < 8; ++c) {
        __syncthreads();
        if (c < 7) STAGE(c + 1, buf ^ 1);
#pragma unroll
        for (int ks = 0; ks < 3; ++ks) {
            const int ko = ks * 32 + kg;
            bf16x8 ah = *(const bf16x8*)&Ah[buf][(w * 16 + lr) * LDB + ko];
            bf16x8 al = *(const bf16x8*)&Al[buf][(w * 16 + lr) * LDB + ko];
#pragma unroll
            for (int j = 0; j < 4; ++j) {
                bf16x8 bb = *(const bf16x8*)&Bl[buf][(j * 16 + lr) * LDB + ko];
                acc[j] = __builtin_amdgcn_mfma_f32_16x16x32_bf16(ah, bb, acc[j], 0, 0, 0);
                acc[j] = __builtin_amdgcn_mfma_f32_16x16x32_bf16(al, bb, acc[j], 0, 0, 0);
            }
        }
        buf ^= 1;
    }

    // C/D mapping (m89-verified): col = lane&15, row = (lane>>4)*4 + reg
#pragma unroll
    for (int j = 0; j < 4; ++j) {
        const int col = j * 16 + lr;
#pragma unroll
        for (int r = 0; r < 4; ++r) {
            const int row = n0 + w * 16 + (l >> 4) * 4 + r;
            if (col < 32)
                Qh[(size_t)row * 128 + (b << 5) + col] = f2bf(acc[j][r] * INV_SQRT_DK);
            else
                Kh[(size_t)row * 128 + (b << 5) + (col - 32)] = f2bf(acc[j][r]);
        }
    }
}

// ---------------------------------------------------------------------------
// 2) S = Q @ K^T via MFMA 16x16x32 bf16. 128x128 tile per 256-thread block,
//    wave tile 64x64 (4x4 frags), 2-deep register ping-pong prefetch.
// ---------------------------------------------------------------------------
template<bool B16>
__global__ __launch_bounds__(256, 3) void gemm_kernel(
    const short* __restrict__ Qh, const short* __restrict__ Kh, void* Sv)
{
    const int bi = blockIdx.x >> 5, bj = blockIdx.x & 31;
    const int tid = threadIdx.x;
    const int w = tid >> 6, l = tid & 63;
    const int m0 = bi * 128 + (w >> 1) * 64;
    const int n0 = bj * 128 + (w & 1) * 64;
    const int lr = l & 15;
    const int kg = (l >> 4) * 8;

    f32x4 acc[4][4];
#pragma unroll
    for (int i = 0; i < 4; ++i)
#pragma unroll
        for (int j = 0; j < 4; ++j) acc[i][j] = (f32x4){0.f, 0.f, 0.f, 0.f};

    bf16x8 aA[4], bA[4], aB[4], bB[4];

    auto LD = [&](bf16x8* A, bf16x8* B, int k0) {
#pragma unroll
        for (int i = 0; i < 4; ++i) {
            A[i] = *(const bf16x8*)(Qh + (size_t)(m0 + i * 16 + lr) * 128 + k0 + kg);
            B[i] = *(const bf16x8*)(Kh + (size_t)(n0 + i * 16 + lr) * 128 + k0 + kg);
        }
    };
    auto DOMFMA = [&](bf16x8* A, bf16x8* B) {
#pragma unroll
        for (int i = 0; i < 4; ++i)
#pragma unroll
            for (int j = 0; j < 4; ++j)
                acc[i][j] = __builtin_amdgcn_mfma_f32_16x16x32_bf16(A[i], B[j], acc[i][j], 0, 0, 0);
    };

    LD(aA, bA, 0);
    LD(aB, bB, 32);
    DOMFMA(aA, bA);  LD(aA, bA, 64);
    DOMFMA(aB, bB);  LD(aB, bB, 96);
    DOMFMA(aA, bA);
    DOMFMA(aB, bB);

    // C/D mapping (m89-verified): col = lane&15, row = (lane>>4)*4 + reg
#pragma unroll
    for (int i = 0; i < 4; ++i) {
        int rowb = m0 + i * 16 + (l >> 4) * 4;
#pragma unroll
        for (int j = 0; j < 4; ++j) {
            int col = n0 + j * 16 + (l & 15);
#pragma unroll
            for (int r = 0; r < 4; ++r) {
                if constexpr (B16)
                    ((unsigned short*)Sv)[(size_t)(rowb + r) * NN + col] =
                        (unsigned short)f2bf(acc[i][j][r]);
                else
                    ((float*)Sv)[(size_t)(rowb + r) * NN + col] = acc[i][j][r];
            }
        }
    }
}

// ---------------------------------------------------------------------------
// 3) Fused row stats + dropout-mask extraction + SUBSAMPLED histogram.
//    One wave per row, row in registers. The 67 MB u-read moved here (hides
//    under the atomic phase); emits 1 bit/elem mask for final. Histogram bins
//    only 1/4 of elements (k scaled): threshold error <= 2 bins ~ 4e-5.
// ---------------------------------------------------------------------------
template<bool B16>
__global__ __launch_bounds__(512) void histstat_kernel(
    const void* __restrict__ Sv, const float4* __restrict__ u4,
    float2* __restrict__ stats, unsigned* __restrict__ gh,
    unsigned char* __restrict__ maskb)
{
    __shared__ unsigned h[1024];
    const int tid = threadIdx.x;
    const int l = tid & 63;
    const int w = tid >> 6;

    for (int i = tid; i < 1024; i += 512) h[i] = 0;
    __syncthreads();

#pragma unroll
    for (int r = 0; r < 2; ++r) {
        const int row = (blockIdx.x << 4) + (r << 3) + w;
        const float4* __restrict__ Urow = u4 + (size_t)row * 1024;
        unsigned char* __restrict__ mrow = maskb + ((size_t)row << 9);

        float v[64];
        if constexpr (B16) {
            const u16x8* rp = (const u16x8*)((const unsigned short*)Sv + (size_t)row * NN);
#pragma unroll
            for (int j = 0; j < 8; ++j) {
                u16x8 e = rp[l + (j << 6)];
#pragma unroll
                for (int i = 0; i < 8; ++i) v[j * 8 + i] = bf2f((short)e[i]);
            }
        } else {
            const float4* rp = (const float4*)((const float*)Sv + (size_t)row * NN);
#pragma unroll
            for (int j = 0; j < 16; ++j) {
                float4 t = rp[l + (j << 6)];
                v[j * 4 + 0] = t.x; v[j * 4 + 1] = t.y;
                v[j * 4 + 2] = t.z; v[j * 4 + 3] = t.w;
            }
        }

        float m = -3.4e38f;
#pragma unroll
        for (int j = 0; j < 64; ++j) m = fmaxf(m, v[j]);
#pragma unroll
        for (int off = 32; off; off >>= 1) m = fmaxf(m, __shfl_xor(m, off));

        float s = 0.f;
#pragma unroll
        for (int j = 0; j < 64; ++j) { v[j] = __expf(v[j] - m); s += v[j]; }
#pragma unroll
        for (int off = 32; off; off >>= 1) s += __shfl_xor(s, off);
        const float inv = 1.0f / s;
        if (l == 0) stats[row] = make_float2(m, inv);

        // dropout mask: 1 bit per element, byte = 8 consecutive elements
        if constexpr (B16) {
#pragma unroll
            for (int j = 0; j < 8; ++j) {
                float4 ua = Urow[2 * (l + (j << 6))];
                float4 ub = Urow[2 * (l + (j << 6)) + 1];
                unsigned mb = (ua.x >= 0.1f ? 1u : 0u)  | (ua.y >= 0.1f ? 2u : 0u)
                            | (ua.z >= 0.1f ? 4u : 0u)  | (ua.w >= 0.1f ? 8u : 0u)
                            | (ub.x >= 0.1f ? 16u : 0u) | (ub.y >= 0.1f ? 32u : 0u)
                            | (ub.z >= 0.1f ? 64u : 0u) | (ub.w >= 0.1f ? 128u : 0u);
                mrow[l + (j << 6)] = (unsigned char)mb;
            }
        } else {
#pragma unroll
            for (int j = 0; j < 16; ++j) {
                float4 ua = Urow[l + (j << 6)];
                unsigned nib = (ua.x >= 0.1f ? 1u : 0u) | (ua.y >= 0.1f ? 2u : 0u)
                             | (ua.z >= 0.1f ? 4u : 0u) | (ua.w >= 0.1f ? 8u : 0u);
                unsigned other = (unsigned)__shfl_xor((int)nib, 1);
                if (!(l & 1))
                    mrow[(l >> 1) + (j << 5)] = (unsigned char)(nib | (other << 4));
            }
        }

        // subsampled histogram: 1/4 of elements
        if constexpr (B16) {
#pragma unroll
            for (int jj = 0; jj < 2; ++jj) {
                const int base = jj * 32;   // v[0..7], v[32..39]
#pragma unroll
                for (int c = 0; c < 8; ++c) {
                    int b0 = min(max((int)(__float_as_uint(v[base + c] * inv) >> 16) - 0x3780, 0), 1023);
                    atomicAdd(&h[b0], 1u);
                }
            }
        } else {
#pragma unroll
            for (int jj = 0; jj < 4; ++jj) {
                const int base = jj * 16;   // groups 0,4,8,12
#pragma unroll
                for (int c = 0; c < 4; ++c) {
                    int b0 = min(max((int)(__float_as_uint(v[base + c] * inv) >> 16) - 0x3780, 0), 1023);
                    atomicAdd(&h[b0], 1u);
                }
            }
        }
    }

    __syncthreads();
    unsigned* dst = gh + ((unsigned)blockIdx.x << 10);
    for (int i = tid; i < 1024; i += 512) dst[i] = h[i];   // full overwrite
}

// ---------------------------------------------------------------------------
// 4a) Pre-reduce 256 partials -> 8.   4b) Final reduce + suffix-scan.
// ---------------------------------------------------------------------------
__global__ __launch_bounds__(1024) void reduce_kernel(
    const unsigned* __restrict__ gh, unsigned* __restrict__ gh2)
{
    const int t = threadIdx.x, b = blockIdx.x;
    unsigned s = 0;
    for (int p = 0; p < 32; ++p) s += gh[((unsigned)(b * 32 + p) << 10) + t];
    gh2[((unsigned)b << 10) + t] = s;
}

__global__ __launch_bounds__(1024) void scan_kernel(
    const unsigned* __restrict__ gh2, unsigned* st)
{
    __shared__ unsigned P[1024];
    const int t = threadIdx.x;
    unsigned s = 0;
#pragma unroll
    for (int p = 0; p < 8; ++p) s += gh2[(p << 10) + t];
    P[t] = s;
    __syncthreads();
    for (int off = 1; off < 1024; off <<= 1) {
        unsigned v = P[t] + ((t + off < 1024) ? P[t + off] : 0u);
        __syncthreads();
        P[t] = v;
        __syncthreads();
    }
    if (P[t] >= KSEL_S && (t == 1023 || P[t + 1] < KSEL_S))
        st[2] = (0x3780u + (unsigned)t) << 16;   // lower edge of selected bin
}

// ---------------------------------------------------------------------------
// 5) Final: recompute p; threshold -> keep; else dropout via 1-bit mask
//    (u-read replaced by 2 MB mask -> 102.5 MB total instead of 167.5).
// ---------------------------------------------------------------------------
template<bool B16>
__global__ __launch_bounds__(256) void final_kernel(
    const void* __restrict__ Sv, float* __restrict__ out,
    const unsigned* __restrict__ maskw,
    const float2* __restrict__ stats, const unsigned* __restrict__ st)
{
    const int row = blockIdx.x;
    const int tid = threadIdx.x;
    const float thr = __uint_as_float(st[2]);
    const float2 stt = stats[row];
    float4* o4 = (float4*)(out + (size_t)row * NN);
    const unsigned* mw = maskw + (size_t)row * 128;

    float4 sv[4];
    unsigned wv[4];

    if constexpr (B16) {
        const ushort4* S4 = (const ushort4*)((const unsigned short*)Sv + (size_t)row * NN);
        ushort4 sraw[4];
#pragma unroll
        for (int j = 0; j < 4; ++j) sraw[j] = S4[tid + (j << 8)];
#pragma unroll
        for (int j = 0; j < 4; ++j) wv[j] = mw[(tid >> 3) + (j << 5)];
#pragma unroll
        for (int j = 0; j < 4; ++j) {
            sv[j].x = bf2f((short)sraw[j].x); sv[j].y = bf2f((short)sraw[j].y);
            sv[j].z = bf2f((short)sraw[j].z); sv[j].w = bf2f((short)sraw[j].w);
        }
    } else {
        const float4* S4 = (const float4*)((const float*)Sv + (size_t)row * NN);
#pragma unroll
        for (int j = 0; j < 4; ++j) sv[j] = S4[tid + (j << 8)];
#pragma unroll
        for (int j = 0; j < 4; ++j) wv[j] = mw[(tid >> 3) + (j << 5)];
    }

    const unsigned sh = (tid & 7) << 2;
#pragma unroll
    for (int j = 0; j < 4; ++j) {
        const unsigned bits = (wv[j] >> sh) & 0xFu;
        float4 o;
        float p;
        p = __expf(sv[j].x - stt.x) * stt.y;
        o.x = (p >= thr) ? p : ((bits & 1u) ? p * (1.0f / 0.9f) : 0.0f);
        p = __expf(sv[j].y - stt.x) * stt.y;
        o.y = (p >= thr) ? p : ((bits & 2u) ? p * (1.0f / 0.9f) : 0.0f);
        p = __expf(sv[j].z - stt.x) * stt.y;
        o.z = (p >= thr) ? p : ((bits & 4u) ? p * (1.0f / 0.9f) : 0.0f);
        p = __expf(sv[j].w - stt.x) * stt.y;
        o.w = (p >= thr) ? p : ((bits & 8u) ? p * (1.0f / 0.9f) : 0.0f);
        o4[tid + (j << 8)] = o;
    }
}

extern "C" void kernel_launch(void* const* d_in, const int* in_sizes, int n_in,
                              void* d_out, int out_size, void* d_ws, size_t ws_size,
                              hipStream_t stream)
{
    const float* x  = (const float*)d_in[0];
    const float* WQ = (const float*)d_in[1];
    const float* WK = (const float*)d_in[2];
    const float* du = (const float*)d_in[3];
    float* out = (float*)d_out;
    char* ws = (char*)d_ws;

    short* Qh = (short*)(ws + OFF_QH);
    short* Kh = (short*)(ws + OFF_KH);
    float2* stats = (float2*)(ws + OFF_STATS);
    unsigned* hist = (unsigned*)(ws + OFF_H);
    unsigned* gh2  = (unsigned*)(ws + OFF_H2);
    unsigned* st   = (unsigned*)(ws + OFF_ST);
    unsigned char* mask = (unsigned char*)(ws + OFF_MASK);

    proj_kernel<<<256, 256, 0, stream>>>(x, WQ, WK, Qh, Kh);

    const bool b16 = (ws_size >= (size_t)WS_NEED_B16);   // fixed per process -> graph-safe
    if (b16) {
        void* Sb = (void*)(ws + OFF_SB);
        gemm_kernel<true><<<1024, 256, 0, stream>>>(Qh, Kh, Sb);
        histstat_kernel<true><<<256, 512, 0, stream>>>(Sb, (const float4*)du, stats, hist, mask);
        reduce_kernel<<<8, 1024, 0, stream>>>(hist, gh2);
        scan_kernel<<<1, 1024, 0, stream>>>(gh2, st);
        final_kernel<true><<<NN, 256, 0, stream>>>(Sb, out, (const unsigned*)mask, stats, st);
    } else {
        gemm_kernel<false><<<1024, 256, 0, stream>>>(Qh, Kh, (void*)out);
        histstat_kernel<false><<<256, 512, 0, stream>>>((void*)out, (const float4*)du, stats, hist, mask);
        reduce_kernel<<<8, 1024, 0, stream>>>(hist, gh2);
        scan_kernel<<<1, 1024, 0, stream>>>(gh2, st);
        final_kernel<false><<<NN, 256, 0, stream>>>((void*)out, out, (const unsigned*)mask, stats, st);
    }
}